// Round 1
// baseline (692.584 us; speedup 1.0000x reference)
//
#include <hip/hip_runtime.h>
#include <math.h>

#define BB 8
#define CC 256
#define KK 19
#define HW 16384
#define HW4 4096          // HW / 4 (float4 units)
#define CTILE 4
#define BLOCK 256
#define ITERS (HW4 / BLOCK)   // 16

__global__ void CGM_4432406249585_kernel(
    const float* __restrict__ feature,
    const float* __restrict__ map_,
    const float* __restrict__ gamma,
    float* __restrict__ out)
{
    // b = blockIdx % 8: round-robin dispatch puts same-batch blocks on the
    // same XCD, so the 1.25 MB per-batch map tile stays resident in that
    // XCD's 4 MiB L2 across the 64 c-tiles that re-read it.
    const int b  = blockIdx.x % BB;
    const int ct = blockIdx.x / BB;
    const int c0 = ct * CTILE;
    const int t  = threadIdx.x;

    const float4* f4 = (const float4*)(feature + ((size_t)b * CC + c0) * HW);
    const float4* m4 = (const float4*)(map_    + (size_t)b * KK * HW);
    float4*       o4 = (float4*)      (out     + ((size_t)b * CC + c0) * HW);

    float acc[CTILE][KK];
#pragma unroll
    for (int c = 0; c < CTILE; ++c)
#pragma unroll
        for (int k = 0; k < KK; ++k) acc[c][k] = 0.f;

    // Pass 1: contraction. Coalesced float4 loads; 19 map loads + 4 feature
    // loads + 304 FMAs per iteration per thread.
    for (int j = 0; j < ITERS; ++j) {
        const int i = t + j * BLOCK;
        float4 f[CTILE];
#pragma unroll
        for (int c = 0; c < CTILE; ++c)
            f[c] = f4[(size_t)c * HW4 + i];
#pragma unroll
        for (int k = 0; k < KK; ++k) {
            const float4 m = m4[(size_t)k * HW4 + i];
#pragma unroll
            for (int c = 0; c < CTILE; ++c) {
                acc[c][k] += f[c].x * m.x + f[c].y * m.y
                           + f[c].z * m.z + f[c].w * m.w;
            }
        }
    }

    // Wave-level butterfly reduce each accumulator across 64 lanes.
#pragma unroll
    for (int c = 0; c < CTILE; ++c)
#pragma unroll
        for (int k = 0; k < KK; ++k) {
            float v = acc[c][k];
#pragma unroll
            for (int off = 32; off >= 1; off >>= 1)
                v += __shfl_xor(v, off, 64);
            acc[c][k] = v;
        }

    __shared__ float partial[4][CTILE * KK];   // 4 waves per block
    __shared__ float gbuf[CTILE * KK];
    __shared__ float scale[CTILE];

    const int wave = t >> 6;
    const int lane = t & 63;
    if (lane == 0) {
#pragma unroll
        for (int c = 0; c < CTILE; ++c)
#pragma unroll
            for (int k = 0; k < KK; ++k)
                partial[wave][c * KK + k] = acc[c][k];
    }
    __syncthreads();

    if (t < CTILE * KK) {
        const float att = partial[0][t] + partial[1][t]
                        + partial[2][t] + partial[3][t];
        const float sig = 1.f / (1.f + __expf(-att));
        gbuf[t] = sig * gamma[t % KK];
    }
    __syncthreads();

    if (t < CTILE) {
        float s = 0.f;
#pragma unroll
        for (int k = 0; k < KK; ++k) s += gbuf[t * KK + k];
        scale[t] = 1.f + s;
    }
    __syncthreads();

    float sc[CTILE];
#pragma unroll
    for (int c = 0; c < CTILE; ++c) sc[c] = scale[c];

    // Pass 2: re-read this block's own 256 KB feature slice (L2/L3-warm),
    // apply the gate, write out.
    for (int j = 0; j < ITERS; ++j) {
        const int i = t + j * BLOCK;
#pragma unroll
        for (int c = 0; c < CTILE; ++c) {
            const float4 f = f4[(size_t)c * HW4 + i];
            float4 r;
            r.x = f.x * sc[c];
            r.y = f.y * sc[c];
            r.z = f.z * sc[c];
            r.w = f.w * sc[c];
            o4[(size_t)c * HW4 + i] = r;
        }
    }
}

extern "C" void kernel_launch(void* const* d_in, const int* in_sizes, int n_in,
                              void* d_out, int out_size, void* d_ws, size_t ws_size,
                              hipStream_t stream) {
    const float* feature = (const float*)d_in[0];
    const float* map_    = (const float*)d_in[1];
    const float* gamma   = (const float*)d_in[2];
    float* out           = (float*)d_out;

    const int grid = BB * (CC / CTILE);   // 512 blocks
    CGM_4432406249585_kernel<<<grid, BLOCK, 0, stream>>>(feature, map_, gamma, out);
}